// Round 10
// baseline (167.228 us; speedup 1.0000x reference)
//
#include <hip/hip_runtime.h>

// Problem constants (fixed by setup_inputs)
constexpr int Bn = 128, Cn = 3, Sn = 256;
constexpr int HWn = Sn * Sn;          // 65536
constexpr int NPLANE = Bn * Cn;       // 384
constexpr float DTf = 0.05f;
constexpr float EPSf = 1e-6f;
constexpr float MAXCf = 1.0f;

// ws float layout:
//   [8..25]        r[step][dir][c] (18)
//   [32..127]      means partials (6 groups x 16 blocks)
//   [128..4735]    cp tables [18][256] (cp[255] = TRUE value)
//   [4736..9343]   dinv tables [18][256]
//   [9344..13951]  cdy: y-dir (cp,dinv) float2 [9][256]  (index = step*3+c)
#define WS_R    8
#define WS_PART 32
#define WS_CP   128
#define WS_DINV 4736
#define WS_CDY  9344

__global__ void means_part(const float* __restrict__ aspat,
                           const float* __restrict__ bspat,
                           float* __restrict__ ws) {
  int grp = blockIdx.x >> 4;   // 0..5 = dir*3 + c
  int sub = blockIdx.x & 15;
  const float* base = (grp < 3) ? (aspat + grp * HWn) : (bspat + (grp - 3) * HWn);
  const float4* p = (const float4*)base + sub * 1024 + threadIdx.x;
  double acc = 0.0;
#pragma unroll
  for (int k = 0; k < 4; ++k) {
    float4 v = p[k * 256];
    acc += (double)v.x + (double)v.y + (double)v.z + (double)v.w;
  }
  __shared__ double sm[256];
  sm[threadIdx.x] = acc;
  __syncthreads();
  for (int s = 128; s > 0; s >>= 1) {
    if (threadIdx.x < s) sm[threadIdx.x] += sm[threadIdx.x + s];
    __syncthreads();
  }
  if (threadIdx.x == 0) ws[WS_PART + blockIdx.x] = (float)sm[0];
}

// One thread per (step, dir, channel): build cp[256], dinv[256] (+ interleaved
// y-table), r.
__global__ void coeff_kernel(const float* __restrict__ alpha_base,
                             const float* __restrict__ beta_base,
                             float* __restrict__ ws) {
  int id = threadIdx.x;
  if (id >= 18) return;
  int s = id / 6, dir = (id / 3) % 2, c = id % 3;
  double msum = 0.0;
  for (int k = 0; k < 16; ++k) msum += (double)ws[WS_PART + (dir * 3 + c) * 16 + k];
  float mean = (float)(msum * (1.0 / HWn));
  float t = (float)s * DTf;
  float base = (dir == 0) ? alpha_base[c] : beta_base[c];
  float coef = fminf(fmaxf(base + mean * t, EPSf), MAXCf);
  float r = coef * (DTf * 0.5f);  // DX = 1
  ws[WS_R + id] = r;
  float* cp = ws + WS_CP + id * 256;
  float* dinv = ws + WS_DINV + id * 256;
  float2* cdy = (float2*)(ws + WS_CDY) + (s * 3 + c) * 256;  // used iff dir==1
  float b0 = 1.0f + r;
  float bi = 1.0f + 2.0f * r;
  dinv[0] = 1.0f / (b0 + EPSf);
  cp[0] = -r / (b0 + EPSf);
  if (dir == 1) cdy[0] = make_float2(cp[0], dinv[0]);
  for (int i = 1; i < 256; ++i) {
    float b = (i == 255) ? b0 : bi;
    float denom = fmaxf(b + r * cp[i - 1], EPSf);  // b - a*cp_prev, a=-r
    cp[i] = -r / denom;
    dinv[i] = 1.0f / denom;
    if (dir == 1) cdy[i] = make_float2(cp[i], dinv[i]);
  }
  // cp[255] TRUE: forward uses -cp[i]==r*dinv[i] at all i; back-substitution
  // never multiplies cp[255] (x_top = dp_top explicitly).
}

// ------------- Fully-fused kernel: 3 ADI steps (6 solves) in one pass -------
// Block = (plane, half): W=134-row x 256-col LDS window, core 128 rows,
// halo 6 on the cut side (3 y-solves x 2-row halo; trunc err ~4e-7 local,
// ~5e-11 at output). ONE 1024-thread block (16 waves) per CU — guaranteed
// residency at VGPR<=128 (R8/R9 showed 2x512-block residency needs VGPR<=64).
// diag applied to the field at the END of EVERY step.
// LDS swizzle (involution, quad-granular): (rl,col) at word
//   rl*256 + ((colq ^ (rl&7))<<2 | col&3).
__global__ __launch_bounds__(1024, 4) void fused3(
    const float* __restrict__ src, float* __restrict__ dst,
    const float* __restrict__ ws, const float* __restrict__ coupling) {
  constexpr int W = 134;
  __shared__ float tile[W * 256];            // 137216 B
  const int t = threadIdx.x;
  // XCD-bijective swizzle: 768 = 8*96; plane-halves paired on one XCD.
  const int logical = (blockIdx.x & 7) * 96 + (blockIdx.x >> 3);
  const int plane = logical >> 1;            // b*3 + c
  const int h = logical & 1;                 // half: core rows [128h,128h+128)
  const int c = plane % 3;
  const int a0 = h ? 122 : 0;                // window start (global row)

  // ---- DMA all W rows (linear LDS dest, inverse-swizzled global source) ----
  {
    const int wv = t >> 6, l = t & 63;
    const float* srcp = src + (size_t)plane * HWn;
#pragma unroll
    for (int j = 0; j < 9; ++j) {
      const int rl = wv + 16 * j;
      if (rl < W) {
        const float* gp = srcp + (size_t)(a0 + rl) * 256 + ((l ^ (rl & 7)) << 2);
        __builtin_amdgcn_global_load_lds(
            (const __attribute__((address_space(1))) void*)gp,
            (__attribute__((address_space(3))) void*)(tile + rl * 256), 16, 0, 0);
      }
    }
  }
  const float dg = coupling[c * 3 + c];      // uniform scalar load
  asm volatile("s_waitcnt vmcnt(0)" ::: "memory");
  __syncthreads();

  for (int k = 0; k < 3; ++k) {
    // ====== x-solve: 7 chunks x 134 rows = 938 units, 13-quad windows ======
    // cores (quads): {[0,9),[9,18),[18,27),[27,36),[36,45),[45,54),[54,64)}
    // windows: qs = {0,7,16,25,34,43,51}, all length 13; halo >= 2 quads.
    {
      const int cw = t / 134;                // per-lane chunk (0..6; 7=idle)
      const int rw = t - 134 * cw;
      const int xlo = h ? 2 * k : 0;         // rows valid at this step
      const int xhi = h ? W : W - 2 * k;
      const bool act = (cw < 7) && (rw >= xlo) && (rw < xhi);
      const int qs = (cw == 0) ? 0 : (cw == 6) ? 51 : 9 * cw - 2;
      const int off = (cw == 0) ? 0 : (cw == 6) ? 3 : 2;   // core rel start
      const int clen = (cw == 6) ? 10 : 9;
      const float4* cpx = (const float4*)(ws + WS_CP + (size_t)(6 * k + c) * 256) + qs;
      const float4* dix = (const float4*)(ws + WS_DINV + (size_t)(6 * k + c) * 256) + qs;
      float4* trow = (float4*)tile + rw * 64;
      const int sw = rw & 7;
      float4 dq[13];
      if (act) {
        float prev = 0.0f;                   // exact at col 0 (cw0); trunc else
#pragma unroll
        for (int i = 0; i < 13; ++i) {
          const int q = qs + i;
          const float4 v = trow[q ^ sw];
          const float4 cq = cpx[i];
          const float4 eq = dix[i];
          float d0 = fmaf(-cq.x, prev, v.x * eq.x);
          float d1 = fmaf(-cq.y, d0, v.y * eq.y);
          float d2 = fmaf(-cq.z, d1, v.z * eq.z);
          float d3 = fmaf(-cq.w, d2, v.w * eq.w);
          dq[i] = make_float4(d0, d1, d2, d3);
          prev = d3;
        }
      }
      __syncthreads();                       // all fwd halo-reads before writes
      if (act) {
        float x = 0.0f;
#pragma unroll
        for (int i = 12; i >= 0; --i) {
          const int q = qs + i;
          const float4 cq = cpx[i];
          const float4 v = dq[i];
          float x3 = (i == 12) ? v.w : fmaf(-cq.w, x, v.w);  // exact top for cw6
          float x2 = fmaf(-cq.z, x3, v.z);
          float x1 = fmaf(-cq.y, x2, v.y);
          float x0 = fmaf(-cq.x, x1, v.x);
          if (i >= off && i < off + clen) trow[q ^ sw] = make_float4(x0, x1, x2, x3);
          x = x0;
        }
      }
      __syncthreads();
    }
    // ====== y-solve: 8 segs x 128 col-pairs, 24-row windows ======
    {
      const int segu = __builtin_amdgcn_readfirstlane(t >> 7);
      const int pair = t & 127;
      const int j0 = 2 * pair;
      const int vlo = h ? 2 * k : 0;               // valid band
      const int vhi = h ? W : W - 2 * k;
      const int olo = h ? 2 * (k + 1) : 0;         // output band (k=2: == core)
      const int ohi = h ? W : W - 2 * (k + 1);
      const int olen = (ohi - olo + 7) >> 3;
      const int out_lo = olo + segu * olen;
      int out_hi = out_lo + olen; if (out_hi > ohi) out_hi = ohi;
      int hs = out_lo - 2;
      if (hs < vlo) hs = vlo;
      if (hs > vhi - 24) hs = vhi - 24;
      const int wlo = out_lo - hs, whi = out_hi - hs;
      const float2* __restrict__ cdp =
          (const float2*)(ws + WS_CDY) + (size_t)(3 * k + c) * 256 + (a0 + hs);
      const int jq = pair >> 1;
      const int jin = (pair & 1) * 2;
      float* bp[8];
#pragma unroll
      for (int p = 0; p < 8; ++p) {
        const int rl = hs + p;
        bp[p] = tile + rl * 256 + (((jq ^ (rl & 7)) << 2) | jin);
      }
      float2 dp[24];
      float px = 0.0f, py = 0.0f;            // exact at global row 0; trunc else
#pragma unroll
      for (int o = 0; o < 3; ++o) {
#pragma unroll
        for (int p = 0; p < 8; ++p) {
          const int i = 8 * o + p;
          const float2 cd = cdp[i];          // scalar (SGPR) loads
          const float2 v = *(const float2*)(bp[p] + o * 2048);
          px = fmaf(-cd.x, px, v.x * cd.y);
          py = fmaf(-cd.x, py, v.y * cd.y);
          dp[i] = make_float2(px, py);
        }
      }
      __syncthreads();                       // all fwd reads before bwd writes
      float xx = 0.0f, xy = 0.0f;
      if (k == 2) {
        float* dstp = dst + (size_t)plane * HWn + (size_t)(a0 + hs) * 256 + j0;
#pragma unroll
        for (int i = 23; i >= 0; --i) {
          if (i == 23) { xx = dp[23].x; xy = dp[23].y; }   // exact at row 255
          else {
            const float cpi = cdp[i].x;
            xx = fmaf(-cpi, xx, dp[i].x);
            xy = fmaf(-cpi, xy, dp[i].y);
          }
          if (i >= wlo && i < whi)
            *(float2*)(dstp + (size_t)i * 256) = make_float2(xx * dg, xy * dg);
        }
      } else {
#pragma unroll
        for (int o = 2; o >= 0; --o) {
#pragma unroll
          for (int p = 7; p >= 0; --p) {
            const int i = 8 * o + p;
            if (i == 23) { xx = dp[23].x; xy = dp[23].y; }
            else {
              const float cpi = cdp[i].x;
              xx = fmaf(-cpi, xx, dp[i].x);
              xy = fmaf(-cpi, xy, dp[i].y);
            }
            if (i >= wlo && i < whi)
              *(float2*)(bp[p] + o * 2048) = make_float2(xx * dg, xy * dg);
          }
        }
        __syncthreads();
      }
    }
  }
}

extern "C" void kernel_launch(void* const* d_in, const int* in_sizes, int n_in,
                              void* d_out, int out_size, void* d_ws, size_t ws_size,
                              hipStream_t stream) {
  const float* u = (const float*)d_in[0];
  const float* alpha_base = (const float*)d_in[1];
  const float* beta_base = (const float*)d_in[2];
  const float* alpha_spatial = (const float*)d_in[3];
  const float* beta_spatial = (const float*)d_in[4];
  const float* coupling = (const float*)d_in[5];
  float* out = (float*)d_out;
  float* ws = (float*)d_ws;

  means_part<<<96, 256, 0, stream>>>(alpha_spatial, beta_spatial, ws);
  coeff_kernel<<<1, 64, 0, stream>>>(alpha_base, beta_base, ws);
  fused3<<<NPLANE * 2, 1024, 0, stream>>>(u, out, ws, coupling);
}

// Round 11
// 130.126 us; speedup vs baseline: 1.2851x; 1.2851x over previous
//
#include <hip/hip_runtime.h>

// Problem constants (fixed by setup_inputs)
constexpr int Bn = 128, Cn = 3, Sn = 256;
constexpr int HWn = Sn * Sn;          // 65536
constexpr int NPLANE = Bn * Cn;       // 384
constexpr float DTf = 0.05f;
constexpr float EPSf = 1e-6f;
constexpr float MAXCf = 1.0f;

// ws float layout:
//   [32..127]      means partials (6 groups x 16 blocks)
//   [128..2503]    x cp tables  [9][264]: 1 zero-pad quad each side, real at [4,260)
//   [2560..4935]   x dinv tables [9][264]
//   [5120..10303]  y (cp,dinv) float2 tables [9][288]: zeros at [0,2) and [258,288),
//                  real rows g at [2+g]  (index = step*3+c)
#define WS_PART 32
#define WS_CPX  128
#define WS_DIX  2560
#define WS_CDY  5120

__global__ void means_part(const float* __restrict__ aspat,
                           const float* __restrict__ bspat,
                           float* __restrict__ ws) {
  int grp = blockIdx.x >> 4;   // 0..5 = dir*3 + c
  int sub = blockIdx.x & 15;
  const float* base = (grp < 3) ? (aspat + grp * HWn) : (bspat + (grp - 3) * HWn);
  const float4* p = (const float4*)base + sub * 1024 + threadIdx.x;
  double acc = 0.0;
#pragma unroll
  for (int k = 0; k < 4; ++k) {
    float4 v = p[k * 256];
    acc += (double)v.x + (double)v.y + (double)v.z + (double)v.w;
  }
  __shared__ double sm[256];
  sm[threadIdx.x] = acc;
  __syncthreads();
  for (int s = 128; s > 0; s >>= 1) {
    if (threadIdx.x < s) sm[threadIdx.x] += sm[threadIdx.x + s];
    __syncthreads();
  }
  if (threadIdx.x == 0) ws[WS_PART + blockIdx.x] = (float)sm[0];
}

// One thread per (step, dir, channel): build zero-padded cp/dinv tables.
// Pads give (a) exact chain starts at the true boundaries (rows/cols 0 and
// 255: dp=0 through pads, x=0 entering from pads) and (b) uniform unrolled
// window code with no clamping of coefficients.
__global__ void coeff_kernel(const float* __restrict__ alpha_base,
                             const float* __restrict__ beta_base,
                             float* __restrict__ ws) {
  int id = threadIdx.x;
  if (id >= 18) return;
  int st = id / 6, dir = (id / 3) % 2, c = id % 3;
  double msum = 0.0;
  for (int k = 0; k < 16; ++k) msum += (double)ws[WS_PART + (dir * 3 + c) * 16 + k];
  float mean = (float)(msum * (1.0 / HWn));
  float t = (float)st * DTf;
  float base = (dir == 0) ? alpha_base[c] : beta_base[c];
  float coef = fminf(fmaxf(base + mean * t, EPSf), MAXCf);
  float r = coef * (DTf * 0.5f);  // DX = 1
  float b0 = 1.0f + r;
  float bi = 1.0f + 2.0f * r;
  float cq = -r / (b0 + EPSf);
  float dq = 1.0f / (b0 + EPSf);
  if (dir == 0) {
    float* cp = ws + WS_CPX + (size_t)(st * 3 + c) * 264;
    float* di = ws + WS_DIX + (size_t)(st * 3 + c) * 264;
#pragma unroll
    for (int i = 0; i < 4; ++i) { cp[i] = 0.f; di[i] = 0.f; cp[260 + i] = 0.f; di[260 + i] = 0.f; }
    cp[4] = cq; di[4] = dq;
    float prev = cq;
    for (int i = 1; i < 256; ++i) {
      float b = (i == 255) ? b0 : bi;
      float denom = fmaxf(b + r * prev, EPSf);  // b - a*cp_prev, a=-r
      prev = -r / denom;
      cp[4 + i] = prev;
      di[4 + i] = 1.0f / denom;
    }
  } else {
    float2* cd = (float2*)(ws + WS_CDY) + (size_t)(st * 3 + c) * 288;
    cd[0] = make_float2(0.f, 0.f);
    cd[1] = make_float2(0.f, 0.f);
    for (int i = 258; i < 288; ++i) cd[i] = make_float2(0.f, 0.f);
    cd[2] = make_float2(cq, dq);
    float prev = cq;
    for (int i = 1; i < 256; ++i) {
      float b = (i == 255) ? b0 : bi;
      float denom = fmaxf(b + r * prev, EPSf);
      prev = -r / denom;
      cd[2 + i] = make_float2(prev, 1.0f / denom);
    }
  }
}

// ------------- Fully-fused kernel: 3 ADI steps (6 solves) in one pass -------
// Block = (plane, stripe): W-row x 256-col LDS tile (W=76 interior, 70 edges),
// core 64 rows. Halo-truncation >= 2 rows (absmax 3.8e-6 proven). diag applied
// to the field at the END of EVERY step. IN-PLACE solves: forward overwrites
// the tile cell with dp, backward with x. Cross-thread overlap rows/quads are
// snapshotted into registers BEFORE one barrier; after it, every access is
// own-band-or-regs — no fwd/bwd barrier needed, per-thread arrays gone,
// everything fits the 64-VGPR budget that (512,4) imposes (R8: 2 blocks/CU).
// LDS swizzle (involution, quad-granular): (rl,col) at word
//   rl*256 + ((colq ^ (rl&7))<<2 | col&3).
__global__ __launch_bounds__(512, 4) void fused3(
    const float* __restrict__ src, float* __restrict__ dst,
    const float* __restrict__ ws, const float* __restrict__ coupling) {
  __shared__ float tile[76 * 256];           // 77824 B
  const int t = threadIdx.x;
  // XCD-bijective swizzle: 1536 = 8*192; same-plane stripes -> same XCD.
  const int logical = (blockIdx.x & 7) * 192 + (blockIdx.x >> 3);
  const int plane = logical >> 2;            // b*3 + c
  const int s = logical & 3;                 // stripe
  const int c = plane % 3;

  const int a0 = (s == 0) ? 0 : ((s == 3) ? 186 : 64 * s - 6);
  const int W = (s == 0 || s == 3) ? 70 : 76;

  // ---- DMA all W rows (linear LDS dest, inverse-swizzled global source) ----
  {
    const int wv = t >> 6, l = t & 63;
    const float* srcp = src + (size_t)plane * HWn;
#pragma unroll
    for (int kk = 0; kk < 10; ++kk) {
      const int rl = wv * 10 + kk;
      if (rl < W) {
        const float* gp = srcp + (size_t)(a0 + rl) * 256 + ((l ^ (rl & 7)) << 2);
        __builtin_amdgcn_global_load_lds(
            (const __attribute__((address_space(1))) void*)gp,
            (__attribute__((address_space(3))) void*)(tile + rl * 256), 16, 0, 0);
      }
    }
  }
  const float dg = coupling[c * 3 + c];      // uniform scalar load
  asm volatile("s_waitcnt vmcnt(0)" ::: "memory");
  __syncthreads();

  for (int k = 0; k < 3; ++k) {
    // ====== x-solve: 4 wave-uniform chunks x 128 rows, 18-quad windows ======
    // window quads [16cw-1, 16cw+17); core (owned) [16cw, 16cw+16) at rel
    // [1,17); rel 0/17 are neighbors' core quads -> pre-read to hv0/hv1.
    // Pad quads (table zeros) give exact starts at cols 0/255.
    {
      const int cw = __builtin_amdgcn_readfirstlane(t >> 7);
      const int rw = t & 127;
      const bool act = rw < W;
      const int qs = 16 * cw - 1;
      const float4* cpx4 = (const float4*)(ws + WS_CPX + (size_t)(3 * k + c) * 264);
      const float4* dix4 = (const float4*)(ws + WS_DIX + (size_t)(3 * k + c) * 264);
      const int sw = rw & 7;
      float4* trow = (float4*)tile + rw * 64;
      float4 hv0, hv1;
      if (act) {
        hv0 = trow[(qs < 0 ? 0 : qs) ^ sw];               // value pad-zeroed if OOB
        const int qt = qs + 17;
        hv1 = trow[(qt > 63 ? 63 : qt) ^ sw];
      }
      __syncthreads();                        // all pre-reads before any write
      if (act) {
        float prev = 0.0f;
#pragma unroll
        for (int i = 0; i < 18; ++i) {        // forward: dp in place
          const int q = qs + i;
          const float4 cq = cpx4[q + 1];
          const float4 eq = dix4[q + 1];
          float4 v = (i == 0) ? hv0 : (i == 17) ? hv1 : trow[q ^ sw];
          float d0 = fmaf(-cq.x, prev, v.x * eq.x);
          float d1 = fmaf(-cq.y, d0, v.y * eq.y);
          float d2 = fmaf(-cq.z, d1, v.z * eq.z);
          float d3 = fmaf(-cq.w, d2, v.w * eq.w);
          float4 dp4 = make_float4(d0, d1, d2, d3);
          if (i == 0) hv0 = dp4;
          else if (i == 17) hv1 = dp4;
          else trow[q ^ sw] = dp4;
          prev = d3;
        }
        float x = 0.0f;
#pragma unroll
        for (int i = 17; i >= 0; --i) {       // backward: x in place (own core)
          const int q = qs + i;
          const float4 cq = cpx4[q + 1];
          float4 dpv = (i == 0) ? hv0 : (i == 17) ? hv1 : trow[q ^ sw];
          float x3 = fmaf(-cq.w, x, dpv.w);
          float x2 = fmaf(-cq.z, x3, dpv.z);
          float x1 = fmaf(-cq.y, x2, dpv.y);
          float x0 = fmaf(-cq.x, x1, dpv.x);
          if (i >= 1 && i <= 16) trow[q ^ sw] = make_float4(x0, x1, x2, x3);
          x = x0;
        }
      }
      __syncthreads();
    }
    // ====== y-solve: 4 segs x 128 col-pairs, 24-row windows, band 18 ======
    // window rows [hs, hs+24), hs = olo+18*seg-2; band (owned) rel [2,20);
    // rel [0,2) + [20,24) are neighbors' bands -> pre-read to hv[6].
    // Table pads handle hs<0 and beyond-255; reads clamp addresses only.
    {
      const int seg = __builtin_amdgcn_readfirstlane(t >> 7);
      const int pair = t & 127;
      const int jq = pair >> 1, jin = (pair & 1) * 2, j0 = 2 * pair;
      const int olo = (s == 0) ? 0 : 2 * (k + 1);
      const int ohi = (s == 3) ? W : W - 2 * (k + 1);
      const int out_lo = olo + 18 * seg;
      const int hs = out_lo - 2;
      const float2* cdp = (const float2*)(ws + WS_CDY) + (size_t)(3 * k + c) * 288
                          + 2 + (a0 + hs);
      float* bpA[8];                          // rows hs+2+p, always in [0,W)
#pragma unroll
      for (int p = 0; p < 8; ++p) {
        const int rl = hs + 2 + p;
        bpA[p] = tile + rl * 256 + (((jq ^ (rl & 7)) << 2) | jin);
      }
      auto addrc = [&](int row) -> float* {   // clamped address (value pad-safe)
        int rl = row < 0 ? 0 : (row > W - 1 ? W - 1 : row);
        return tile + rl * 256 + (((jq ^ (rl & 7)) << 2) | jin);
      };
      float2 hv[6];                           // i<2 -> hv[i]; i>=20 -> hv[i-18]
      hv[0] = *(float2*)addrc(hs + 0);
      hv[1] = *(float2*)addrc(hs + 1);
#pragma unroll
      for (int i2 = 0; i2 < 4; ++i2) hv[2 + i2] = *(float2*)addrc(hs + 20 + i2);
      __syncthreads();                        // all pre-reads before any write
      float px = 0.0f, py = 0.0f;
#pragma unroll
      for (int i = 0; i < 24; ++i) {          // forward: dp in place (band)
        const float2 cd = cdp[i];
        float2 v;
        float* ap = nullptr;
        if (i < 2) v = hv[i];
        else if (i < 10) { ap = bpA[i - 2]; v = *(float2*)ap; }
        else if (i < 18) { ap = bpA[i - 10] + 2048; v = *(float2*)ap; }
        else if (i < 20) { ap = addrc(hs + i); v = *(float2*)ap; }
        else v = hv[i - 18];
        px = fmaf(-cd.x, px, v.x * cd.y);
        py = fmaf(-cd.x, py, v.y * cd.y);
        float2 dp2 = make_float2(px, py);
        if (i < 2) hv[i] = dp2;
        else if (i < 18) *(float2*)ap = dp2;
        else if (i < 20) { if (hs + i < W) *(float2*)ap = dp2; }
        else hv[i - 18] = dp2;
      }
      float xx = 0.0f, xy = 0.0f;             // backward (no barrier needed:
      float* dstp = dst + (size_t)plane * HWn + j0;   // own band + regs only)
#pragma unroll
      for (int i = 23; i >= 0; --i) {
        const float2 cd = cdp[i];
        float2 dpv;
        float* ap = nullptr;
        if (i < 2) dpv = hv[i];
        else if (i < 10) { ap = bpA[i - 2]; dpv = *(float2*)ap; }
        else if (i < 18) { ap = bpA[i - 10] + 2048; dpv = *(float2*)ap; }
        else if (i < 20) { ap = addrc(hs + i); dpv = *(float2*)ap; }
        else dpv = hv[i - 18];
        xx = fmaf(-cd.x, xx, dpv.x);
        xy = fmaf(-cd.x, xy, dpv.y);
        const bool wr = (i >= 2) && (i < 20) && (hs + i < ohi);
        if (k == 2) {
          if (wr) *(float2*)(dstp + (size_t)(a0 + hs + i) * 256) =
              make_float2(xx * dg, xy * dg);
        } else {
          if (wr) *(float2*)ap = make_float2(xx * dg, xy * dg);
        }
      }
      __syncthreads();
    }
  }
}

extern "C" void kernel_launch(void* const* d_in, const int* in_sizes, int n_in,
                              void* d_out, int out_size, void* d_ws, size_t ws_size,
                              hipStream_t stream) {
  const float* u = (const float*)d_in[0];
  const float* alpha_base = (const float*)d_in[1];
  const float* beta_base = (const float*)d_in[2];
  const float* alpha_spatial = (const float*)d_in[3];
  const float* beta_spatial = (const float*)d_in[4];
  const float* coupling = (const float*)d_in[5];
  float* out = (float*)d_out;
  float* ws = (float*)d_ws;

  means_part<<<96, 256, 0, stream>>>(alpha_spatial, beta_spatial, ws);
  coeff_kernel<<<1, 64, 0, stream>>>(alpha_base, beta_base, ws);
  fused3<<<NPLANE * 4, 512, 0, stream>>>(u, out, ws, coupling);
}

// Round 12
// 127.968 us; speedup vs baseline: 1.3068x; 1.0169x over previous
//
#include <hip/hip_runtime.h>

// Problem constants (fixed by setup_inputs)
constexpr int Bn = 128, Cn = 3, Sn = 256;
constexpr int HWn = Sn * Sn;          // 65536
constexpr int NPLANE = Bn * Cn;       // 384
constexpr float DTf = 0.05f;
constexpr float EPSf = 1e-6f;
constexpr float MAXCf = 1.0f;

// ws float layout:
//   [32..127]       means partials (6 groups x 16 blocks)
//   [128..10111]    tapx [3 c][13 d][256 i]
//   [10368..20351]  tapy [3 c][13 d][256 i]  (dg^3 folded in)
#define WS_PART 32
#define WS_TAPX 128
#define WS_TAPY 10368

__global__ void means_part(const float* __restrict__ aspat,
                           const float* __restrict__ bspat,
                           float* __restrict__ ws) {
  int grp = blockIdx.x >> 4;   // 0..5 = dir*3 + c
  int sub = blockIdx.x & 15;
  const float* base = (grp < 3) ? (aspat + grp * HWn) : (bspat + (grp - 3) * HWn);
  const float4* p = (const float4*)base + sub * 1024 + threadIdx.x;
  double acc = 0.0;
#pragma unroll
  for (int k = 0; k < 4; ++k) {
    float4 v = p[k * 256];
    acc += (double)v.x + (double)v.y + (double)v.z + (double)v.w;
  }
  __shared__ double sm[256];
  sm[threadIdx.x] = acc;
  __syncthreads();
  for (int s = 128; s > 0; s >>= 1) {
    if (threadIdx.x < s) sm[threadIdx.x] += sm[threadIdx.x + s];
    __syncthreads();
  }
  if (threadIdx.x == 0) ws[WS_PART + blockIdx.x] = (float)sm[0];
}

// ---- build composed banded operator taps --------------------------------
// All T_k = I + r_k*L commute; composed X (resp Y) = product of the three
// x-dir (y-dir) tridiagonal inverses. Thread j applies the three EXACT
// reference Thomas solves (incl. b0+eps, denom clamp, x_n = dp_n) to basis
// vector e_j, keeping the banded window i in [j-16, j+16] in registers
// (outside values < 1e-30). Row-taps gathered from columns: tap[d][i] =
// X_{i, i-6+d} = column_{i-6+d}[i]. Band +-6 tail ~ 3e-10 (r <= 0.025).
__global__ void build_taps(const float* __restrict__ alpha_base,
                           const float* __restrict__ beta_base,
                           const float* __restrict__ coupling,
                           float* __restrict__ ws) {
  __shared__ float cp3[3][288], di3[3][288];   // padded: idx = i+16, zeros outside [0,255]
  const int dirc = blockIdx.x, dir = dirc / 3, c = dirc % 3;
  const int j = threadIdx.x;
  if (j < 3) {
    const int k = j;
    double ms = 0.0;
    for (int m = 0; m < 16; ++m) ms += (double)ws[WS_PART + dirc * 16 + m];
    float mean = (float)(ms * (1.0 / 65536.0));
    float base = (dir == 0) ? alpha_base[c] : beta_base[c];
    float coef = fminf(fmaxf(base + mean * ((float)k * DTf), EPSf), MAXCf);
    float r = coef * (DTf * 0.5f);             // DX = 1
    for (int p = 0; p < 16; ++p) {
      cp3[k][p] = 0.f; di3[k][p] = 0.f;
      cp3[k][272 + p] = 0.f; di3[k][272 + p] = 0.f;
    }
    float b0 = 1.f + r + EPSf;                 // reference: b[0] + eps
    float cq = -r / b0, dq = 1.f / b0;
    cp3[k][16] = cq; di3[k][16] = dq;
    for (int i = 1; i < 256; ++i) {
      float b = (i == 255) ? (1.f + r) : (1.f + 2.f * r);
      float den = fmaxf(b + r * cq, EPSf);     // b - a*cp_prev, a = -r
      cq = -r / den; dq = 1.f / den;
      cp3[k][16 + i] = cq; di3[k][16 + i] = dq;
    }
  }
  // zero the whole tap table (guards: boundary taps with OOB source stay 0)
  float* tb = ws + ((dir == 0) ? WS_TAPX : WS_TAPY) + c * 13 * 256;
#pragma unroll
  for (int d = 0; d < 13; ++d) tb[d * 256 + j] = 0.f;
  __syncthreads();

  float z[33];                                  // o = 0..32 <-> row i = j-16+o
#pragma unroll
  for (int o = 0; o < 33; ++o) z[o] = (o == 16) ? 1.f : 0.f;
#pragma unroll
  for (int k = 0; k < 3; ++k) {
    float dp = 0.f;
#pragma unroll
    for (int o = 0; o < 33; ++o) {              // forward: dp in place
      const int p = j + o;                      // = (j-16+o) + 16 (padded idx)
      dp = fmaf(-cp3[k][p], dp, z[o] * di3[k][p]);
      z[o] = dp;
    }
    float x = 0.f;
#pragma unroll
    for (int o = 32; o >= 0; --o) {             // backward: x = dp - cp*x_next
      const int p = j + o;
      x = fmaf(-cp3[k][p], x, z[o]);
      z[o] = x;
    }
  }
  float scale = 1.f;
  if (dir == 1) {
    float dgc = coupling[c * 3 + c];
    scale = dgc * dgc * dgc;                    // diag applied after each step
  }
#pragma unroll
  for (int o = -6; o <= 6; ++o) {
    const int i = j + o;                        // output row; d = 6 - o
    if ((unsigned)i < 256u) tb[(6 - o) * 256 + i] = z[o + 16] * scale;
  }
}

// ---- hot kernel: out = Y * u * X^T, separable 13-tap stencil -------------
// Block = (plane, 64-row stripe). Stage 1: x-conv rows [a,b) -> LDS (quad
// swizzle (q ^ (rl&7)) for bank spread). Stage 2: y-conv (taps wave-uniform
// scalar loads) -> coalesced float4 global store. Boundary taps are zero for
// OOB sources, so clamped loads are harmless.
__global__ __launch_bounds__(512, 2) void conv3(
    const float* __restrict__ src, float* __restrict__ dst,
    const float* __restrict__ ws) {
  __shared__ float vt[76 * 256];               // 77824 B -> 2 blocks/CU
  const int t = threadIdx.x;
  // XCD-bijective swizzle: 1536 = 8*192
  const int logical = (blockIdx.x & 7) * 192 + (blockIdx.x >> 3);
  const int plane = logical >> 2;
  const int st = logical & 3;
  const int c = plane % 3;
  const int h0 = st * 64;
  const int a = (st == 0) ? 0 : (h0 - 6);
  const int b = (st == 3) ? 256 : (h0 + 70);
  const int Wv = b - a;                        // 70 or 76
  const float* tpx = ws + WS_TAPX + c * 3328;
  const float* tpy = ws + WS_TAPY + c * 3328;
  float tx[13];                                 // interior x-taps (row 128)
#pragma unroll
  for (int d = 0; d < 13; ++d) tx[d] = tpx[d * 256 + 128];
  const float* srcp = src + (size_t)plane * HWn;

  // ---- stage 1: x-conv. unit = (row rl, 16-col seg s) ----
  const int NU = 16 * Wv;
#pragma unroll
  for (int p = 0; p < 3; ++p) {
    const int u = t + 512 * p;
    if (u < NU) {
      const int s = u & 15, rl = u >> 4;
      const float* row = srcp + (size_t)(a + rl) * 256;
      float in[32];                             // cols [16s-8, 16s+24)
#pragma unroll
      for (int mq = 0; mq < 8; ++mq) {
        int cl = 16 * s - 8 + 4 * mq;
        cl = cl < 0 ? 0 : (cl > 252 ? 252 : cl);
        *(float4*)&in[4 * mq] = *(const float4*)(row + cl);
      }
      float acc[16];
      if (s >= 1 && s <= 14) {                  // interior: taps in SGPRs
#pragma unroll
        for (int e = 0; e < 16; ++e) acc[e] = tx[0] * in[e + 2];
#pragma unroll
        for (int d = 1; d < 13; ++d)
#pragma unroll
          for (int e = 0; e < 16; ++e) acc[e] = fmaf(tx[d], in[e + 2 + d], acc[e]);
      } else {                                  // boundary: per-col taps
#pragma unroll
        for (int e = 0; e < 16; ++e) acc[e] = 0.f;
#pragma unroll
        for (int d = 0; d < 13; ++d) {
          float tv[16];
#pragma unroll
          for (int mq = 0; mq < 4; ++mq)
            *(float4*)&tv[4 * mq] = *(const float4*)(tpx + d * 256 + 16 * s + 4 * mq);
#pragma unroll
          for (int e = 0; e < 16; ++e) acc[e] = fmaf(tv[e], in[e + 2 + d], acc[e]);
        }
      }
      const int sw = rl & 7;
      float4* vr = (float4*)vt + rl * 64;
#pragma unroll
      for (int jj = 0; jj < 4; ++jj)
        vr[(4 * s + jj) ^ sw] =
            make_float4(acc[4 * jj], acc[4 * jj + 1], acc[4 * jj + 2], acc[4 * jj + 3]);
    }
  }
  __syncthreads();

  // ---- stage 2: y-conv. thread = (col-quad q, 8-row chunk rc) ----
  const int q = t & 63, rc = t >> 6;
  const int g0 = h0 + 8 * rc;
  float4 win[13];                               // rows g-6 .. g+6 of quad q
#pragma unroll
  for (int m = 0; m < 12; ++m) {
    int gg = g0 - 6 + m;
    gg = gg < a ? a : gg;                       // clamped read x zero tap
    const int rl = gg - a;
    win[m] = ((const float4*)vt)[rl * 64 + (q ^ (rl & 7))];
  }
  float* dstp = dst + (size_t)plane * HWn + 4 * q;
#pragma unroll
  for (int rr = 0; rr < 8; ++rr) {
    const int g = g0 + rr;
    {
      int gg = g + 6;
      gg = gg > b - 1 ? b - 1 : gg;
      const int rl = gg - a;
      win[12] = ((const float4*)vt)[rl * 64 + (q ^ (rl & 7))];
    }
    const int gu = __builtin_amdgcn_readfirstlane(g);
    float4 o;
    {
      const float ty = tpy[gu];
      o.x = ty * win[0].x; o.y = ty * win[0].y;
      o.z = ty * win[0].z; o.w = ty * win[0].w;
    }
#pragma unroll
    for (int d = 1; d < 13; ++d) {
      const float ty = tpy[d * 256 + gu];       // wave-uniform -> s_load
      o.x = fmaf(ty, win[d].x, o.x);
      o.y = fmaf(ty, win[d].y, o.y);
      o.z = fmaf(ty, win[d].z, o.z);
      o.w = fmaf(ty, win[d].w, o.w);
    }
    *(float4*)(dstp + (size_t)g * 256) = o;
#pragma unroll
    for (int m = 0; m < 12; ++m) win[m] = win[m + 1];
  }
}

extern "C" void kernel_launch(void* const* d_in, const int* in_sizes, int n_in,
                              void* d_out, int out_size, void* d_ws, size_t ws_size,
                              hipStream_t stream) {
  const float* u = (const float*)d_in[0];
  const float* alpha_base = (const float*)d_in[1];
  const float* beta_base = (const float*)d_in[2];
  const float* alpha_spatial = (const float*)d_in[3];
  const float* beta_spatial = (const float*)d_in[4];
  const float* coupling = (const float*)d_in[5];
  float* out = (float*)d_out;
  float* ws = (float*)d_ws;

  means_part<<<96, 256, 0, stream>>>(alpha_spatial, beta_spatial, ws);
  build_taps<<<6, 256, 0, stream>>>(alpha_base, beta_base, coupling, ws);
  conv3<<<NPLANE * 4, 512, 0, stream>>>(u, out, ws);
}

// Round 13
// 89.736 us; speedup vs baseline: 1.8636x; 1.4261x over previous
//
#include <hip/hip_runtime.h>

// Problem constants (fixed by setup_inputs)
constexpr int Bn = 128, Cn = 3, Sn = 256;
constexpr int HWn = Sn * Sn;          // 65536
constexpr int NPLANE = Bn * Cn;       // 384
constexpr float DTf = 0.05f;
constexpr float EPSf = 1e-6f;
constexpr float MAXCf = 1.0f;

// ws float layout:
//   [32..127]       means partials (6 groups x 16 blocks)
//   [128..10111]    tapx [3 c][13 d][256 i]
//   [10368..20351]  tapy [3 c][13 d][256 i]  (dg^3 folded in)
#define WS_PART 32
#define WS_TAPX 128
#define WS_TAPY 10368

__global__ void means_part(const float* __restrict__ aspat,
                           const float* __restrict__ bspat,
                           float* __restrict__ ws) {
  int grp = blockIdx.x >> 4;   // 0..5 = dir*3 + c
  int sub = blockIdx.x & 15;
  const float* base = (grp < 3) ? (aspat + grp * HWn) : (bspat + (grp - 3) * HWn);
  const float4* p = (const float4*)base + sub * 1024 + threadIdx.x;
  double acc = 0.0;
#pragma unroll
  for (int k = 0; k < 4; ++k) {
    float4 v = p[k * 256];
    acc += (double)v.x + (double)v.y + (double)v.z + (double)v.w;
  }
  __shared__ double sm[256];
  sm[threadIdx.x] = acc;
  __syncthreads();
  for (int s = 128; s > 0; s >>= 1) {
    if (threadIdx.x < s) sm[threadIdx.x] += sm[threadIdx.x + s];
    __syncthreads();
  }
  if (threadIdx.x == 0) ws[WS_PART + blockIdx.x] = (float)sm[0];
}

// ---- build composed banded operator taps (UNCHANGED from round 12) -------
__global__ void build_taps(const float* __restrict__ alpha_base,
                           const float* __restrict__ beta_base,
                           const float* __restrict__ coupling,
                           float* __restrict__ ws) {
  __shared__ float cp3[3][288], di3[3][288];   // padded: idx = i+16, zeros outside [0,255]
  const int dirc = blockIdx.x, dir = dirc / 3, c = dirc % 3;
  const int j = threadIdx.x;
  if (j < 3) {
    const int k = j;
    double ms = 0.0;
    for (int m = 0; m < 16; ++m) ms += (double)ws[WS_PART + dirc * 16 + m];
    float mean = (float)(ms * (1.0 / 65536.0));
    float base = (dir == 0) ? alpha_base[c] : beta_base[c];
    float coef = fminf(fmaxf(base + mean * ((float)k * DTf), EPSf), MAXCf);
    float r = coef * (DTf * 0.5f);             // DX = 1
    for (int p = 0; p < 16; ++p) {
      cp3[k][p] = 0.f; di3[k][p] = 0.f;
      cp3[k][272 + p] = 0.f; di3[k][272 + p] = 0.f;
    }
    float b0 = 1.f + r + EPSf;                 // reference: b[0] + eps
    float cq = -r / b0, dq = 1.f / b0;
    cp3[k][16] = cq; di3[k][16] = dq;
    for (int i = 1; i < 256; ++i) {
      float b = (i == 255) ? (1.f + r) : (1.f + 2.f * r);
      float den = fmaxf(b + r * cq, EPSf);     // b - a*cp_prev, a = -r
      cq = -r / den; dq = 1.f / den;
      cp3[k][16 + i] = cq; di3[k][16 + i] = dq;
    }
  }
  float* tb = ws + ((dir == 0) ? WS_TAPX : WS_TAPY) + c * 13 * 256;
#pragma unroll
  for (int d = 0; d < 13; ++d) tb[d * 256 + j] = 0.f;
  __syncthreads();

  float z[33];                                  // o = 0..32 <-> row i = j-16+o
#pragma unroll
  for (int o = 0; o < 33; ++o) z[o] = (o == 16) ? 1.f : 0.f;
#pragma unroll
  for (int k = 0; k < 3; ++k) {
    float dp = 0.f;
#pragma unroll
    for (int o = 0; o < 33; ++o) {              // forward: dp in place
      const int p = j + o;
      dp = fmaf(-cp3[k][p], dp, z[o] * di3[k][p]);
      z[o] = dp;
    }
    float x = 0.f;
#pragma unroll
    for (int o = 32; o >= 0; --o) {             // backward: x = dp - cp*x_next
      const int p = j + o;
      x = fmaf(-cp3[k][p], x, z[o]);
      z[o] = x;
    }
  }
  float scale = 1.f;
  if (dir == 1) {
    float dgc = coupling[c * 3 + c];
    scale = dgc * dgc * dgc;                    // diag applied after each step
  }
#pragma unroll
  for (int o = -6; o <= 6; ++o) {
    const int i = j + o;                        // output row; d = 6 - o
    if ((unsigned)i < 256u) tb[(6 - o) * 256 + i] = z[o + 16] * scale;
  }
}

// ---- hot kernel: out = Y * u * X^T, separable 13-tap stencil -------------
// (512,4): VGPR capped at 64 -> 2 blocks/CU resident (R8/R11-proven envelope).
// Stage 1 (x-conv): 16-col units; all cols via interior taps (SGPR), then
// recompute the 6 true boundary cols (0..5 / 250..255) with per-col taps —
// interior tap band is constant for cols [6,249] (end effect ~2e-10 < ulp).
// Clamped loads only ever pair with zero taps (table zero-padded).
// Stage 2 (y-conv): col-PAIR units, rolling float2 win[13] (26 VGPR, was 52).
// LDS swizzle (involution, quad-granular): (rl,col) at word
//   rl*256 + ((colq ^ (rl&7))<<2 | col&3).
__global__ __launch_bounds__(512, 4) void conv3(
    const float* __restrict__ src, float* __restrict__ dst,
    const float* __restrict__ ws) {
  __shared__ float vt[76 * 256];               // 77824 B
  const int t = threadIdx.x;
  // XCD-bijective swizzle: 1536 = 8*192
  const int logical = (blockIdx.x & 7) * 192 + (blockIdx.x >> 3);
  const int plane = logical >> 2;
  const int st = logical & 3;
  const int c = plane % 3;
  const int h0 = st * 64;
  const int a = (st == 0) ? 0 : (h0 - 6);
  const int b = (st == 3) ? 256 : (h0 + 70);
  const int Wv = b - a;                        // 70 or 76
  const float* tpx = ws + WS_TAPX + c * 3328;
  const float* tpy = ws + WS_TAPY + c * 3328;
  float tx[13];                                 // interior x-taps (uniform addr -> s_load)
#pragma unroll
  for (int d = 0; d < 13; ++d) tx[d] = tpx[d * 256 + 128];
  const float* srcp = src + (size_t)plane * HWn;

  // ---- stage 1: x-conv. unit = (row rl, 16-col seg s) ----
  const int NU = 16 * Wv;
#pragma unroll
  for (int p = 0; p < 3; ++p) {
    const int u = t + 512 * p;
    if (u < NU) {
      const int s = u & 15, rl = u >> 4;
      const float* row = srcp + (size_t)(a + rl) * 256;
      float in_[32];                            // cols [16s-8, 16s+24)
#pragma unroll
      for (int mq = 0; mq < 8; ++mq) {
        int cl = 16 * s - 8 + 4 * mq;
        cl = cl < 0 ? 0 : (cl > 252 ? 252 : cl);
        *(float4*)&in_[4 * mq] = *(const float4*)(row + cl);
      }
      float acc[16];
#pragma unroll
      for (int e = 0; e < 16; ++e) acc[e] = tx[0] * in_[e + 2];
#pragma unroll
      for (int d = 1; d < 13; ++d)
#pragma unroll
        for (int e = 0; e < 16; ++e) acc[e] = fmaf(tx[d], in_[e + 2 + d], acc[e]);
      if (s == 0) {                             // fix cols 0..5 (true taps)
#pragma unroll
        for (int e = 0; e < 6; ++e) {
          float ac = 0.f;
#pragma unroll
          for (int d = 0; d < 13; ++d) ac = fmaf(tpx[d * 256 + e], in_[e + 2 + d], ac);
          acc[e] = ac;
        }
      } else if (s == 15) {                     // fix cols 250..255
#pragma unroll
        for (int e = 10; e < 16; ++e) {
          float ac = 0.f;
#pragma unroll
          for (int d = 0; d < 13; ++d) ac = fmaf(tpx[d * 256 + 240 + e], in_[e + 2 + d], ac);
          acc[e] = ac;
        }
      }
      const int sw = rl & 7;
      float4* vr = (float4*)vt + rl * 64;
#pragma unroll
      for (int jj = 0; jj < 4; ++jj)
        vr[(4 * s + jj) ^ sw] =
            make_float4(acc[4 * jj], acc[4 * jj + 1], acc[4 * jj + 2], acc[4 * jj + 3]);
    }
  }
  __syncthreads();

  // ---- stage 2: y-conv. unit = (col-pair pr, 16-row chunk rc) ----
  const int pr = t & 127, rc = t >> 7;
  const int jq = pr >> 1, jin = (pr & 1) * 2;
  const int g0 = h0 + 16 * rc;
  float2 win[13];                               // rows g-6 .. g+6, one col-pair
#pragma unroll
  for (int m = 0; m < 12; ++m) {
    int gg = g0 - 6 + m;
    gg = gg < a ? a : gg;                       // clamped read x zero tap
    const int rl = gg - a;
    win[m] = *(const float2*)(vt + rl * 256 + (((jq ^ (rl & 7)) << 2) | jin));
  }
  float* dstp = dst + (size_t)plane * HWn + 2 * pr;
#pragma unroll
  for (int rr = 0; rr < 16; ++rr) {
    const int g = g0 + rr;
    {
      int gg = g + 6;
      gg = gg > b - 1 ? b - 1 : gg;
      const int rl = gg - a;
      win[12] = *(const float2*)(vt + rl * 256 + (((jq ^ (rl & 7)) << 2) | jin));
    }
    const int gu = __builtin_amdgcn_readfirstlane(g);
    float ox, oy;
    {
      const float ty = tpy[gu];                 // wave-uniform -> s_load
      ox = ty * win[0].x; oy = ty * win[0].y;
    }
#pragma unroll
    for (int d = 1; d < 13; ++d) {
      const float ty = tpy[d * 256 + gu];
      ox = fmaf(ty, win[d].x, ox);
      oy = fmaf(ty, win[d].y, oy);
    }
    *(float2*)(dstp + (size_t)g * 256) = make_float2(ox, oy);
#pragma unroll
    for (int m = 0; m < 12; ++m) win[m] = win[m + 1];
  }
}

extern "C" void kernel_launch(void* const* d_in, const int* in_sizes, int n_in,
                              void* d_out, int out_size, void* d_ws, size_t ws_size,
                              hipStream_t stream) {
  const float* u = (const float*)d_in[0];
  const float* alpha_base = (const float*)d_in[1];
  const float* beta_base = (const float*)d_in[2];
  const float* alpha_spatial = (const float*)d_in[3];
  const float* beta_spatial = (const float*)d_in[4];
  const float* coupling = (const float*)d_in[5];
  float* out = (float*)d_out;
  float* ws = (float*)d_ws;

  means_part<<<96, 256, 0, stream>>>(alpha_spatial, beta_spatial, ws);
  build_taps<<<6, 256, 0, stream>>>(alpha_base, beta_base, coupling, ws);
  conv3<<<NPLANE * 4, 512, 0, stream>>>(u, out, ws);
}